// Round 3
// baseline (991.784 us; speedup 1.0000x reference)
//
#include <hip/hip_runtime.h>

using u16 = unsigned short;
using s16x8 = __attribute__((ext_vector_type(8))) short;   // 8 bf16 (4 VGPRs)
using f32x4 = __attribute__((ext_vector_type(4))) float;

#define DEVI __device__ __forceinline__

constexpr int AN = 9, NB = 10, NN = 4096, DORI = 2048, DAPP = 512, NCLS = 21, QCOLS = 160;

// output offsets (f32 elements) in return order
constexpr size_t O0 = 0;                 // output            (4096,4)
constexpr size_t O1 = 16384;             // output_beta       (4096,4)
constexpr size_t O2 = 32768;             // alpha_softmax     (9,4096,4)
constexpr size_t O3 = 180224;            // beta_softmax      (9,4096,4)
constexpr size_t O4 = 327680;            // delta_pred_offset (9,4096,4)
constexpr size_t O5 = 475136;            // delta_pred_offset (9,4096,4)
constexpr size_t O6 = 622592;            // alpha             (9,4096,4)
constexpr size_t O7 = 770048;            // beta_out          (9,4096,4)
constexpr size_t O8 = 917504;            // cls_score         (9,4096,21)
constexpr size_t O9 = 1691648;           // alpha_softmax_cls (9,4096,1)
constexpr size_t O10 = 1728512;          // beta_softmax_cls
constexpr size_t O11 = 1765376;          // alpha_cls
constexpr size_t O12 = 1802240;          // beta_out_cls

DEVI u16 f2b(float f) {                   // f32 -> bf16 RNE (internal use only)
  unsigned u = __float_as_uint(f);
  unsigned r = (u + 0x7fffu + ((u >> 16) & 1u)) >> 16;
  return (u16)r;
}

DEVI uint4 pack8(float4 u, float4 v) {    // 8 f32 -> 8 bf16 packed
  uint4 r;
  r.x = (unsigned)f2b(u.x) | ((unsigned)f2b(u.y) << 16);
  r.y = (unsigned)f2b(u.z) | ((unsigned)f2b(u.w) << 16);
  r.z = (unsigned)f2b(v.x) | ((unsigned)f2b(v.y) << 16);
  r.w = (unsigned)f2b(v.z) | ((unsigned)f2b(v.w) << 16);
  return r;
}

// ---------------- attention_feat (2048,512) -> attB (512,2048) bf16 ----------------
__global__ __launch_bounds__(256) void transpose_att(const float* __restrict__ in,
                                                     u16* __restrict__ out) {
  int t = blockIdx.x * blockDim.x + threadIdx.x;
  if (t >= DAPP * DORI) return;
  int c = t / DORI, d = t % DORI;
  out[t] = f2b(in[d * DAPP + c]);
}

// ---------------- pack query/key weights: Wq[b][160][512] bf16 ----------------
// b 0..8: cols 0-127 = w_q[b,d,k,c] (col=k*4+c), cols 128-159 = w_q_cls[b,d,k]
// b 9:    same from w_k / w_k_cls
__global__ __launch_bounds__(256) void pack_q(const float* __restrict__ wq,
                                              const float* __restrict__ wqc,
                                              const float* __restrict__ wk,
                                              const float* __restrict__ wkc,
                                              u16* __restrict__ W) {
  int t = blockIdx.x * blockDim.x + threadIdx.x;
  if (t >= NB * QCOLS * DAPP) return;
  int b = t / (QCOLS * DAPP);
  int r = t % (QCOLS * DAPP);
  int col = r / DAPP, d = r % DAPP;
  float v;
  if (b < 9) {
    if (col < 128) v = wq[(size_t)b * DAPP * 128 + (size_t)d * 128 + col];
    else           v = wqc[(size_t)b * DAPP * 32 + (size_t)d * 32 + (col - 128)];
  } else {
    if (col < 128) v = wk[(size_t)d * 128 + col];
    else           v = wkc[(size_t)d * 32 + (col - 128)];
  }
  W[t] = f2b(v);
}

// ---------------- exact f32 VALU path for alpha/offset/cls/alpha_cls ----------------
// block: (a, 128-row chunk), 256 threads = 128 rows x 2 K-halves
// smallf[a][n][32]: cols 0-3 alpha, 4-7 offset, 8-28 cls, 29 alpha_cls
__global__ __launch_bounds__(256) void small_valu(const float* __restrict__ feat,
                                                  const float* __restrict__ aw,
                                                  const float* __restrict__ bb,
                                                  const float* __restrict__ cw,
                                                  const float* __restrict__ awc,
                                                  float* __restrict__ smallf,
                                                  float* __restrict__ cls_out) {
  const int a = blockIdx.x;
  const int r = threadIdx.x & 127;
  const int row = blockIdx.y * 128 + r;
  const int kh = threadIdx.x >> 7;
  const float* fr = feat + ((size_t)a * NN + row) * DORI + kh * 1024;
  const float* awp = aw + (size_t)a * DORI * 4;
  const float* bbp = bb + (size_t)a * DORI * 4;
  const float* cwp = cw + (size_t)a * DORI * 21;
  const float* awcp = awc + (size_t)a * DORI;

  float acc[30];
#pragma unroll
  for (int i = 0; i < 30; ++i) acc[i] = 0.f;

  for (int k0 = 0; k0 < 1024; k0 += 4) {
    float4 f4 = *(const float4*)(fr + k0);
    float fs[4] = {f4.x, f4.y, f4.z, f4.w};
#pragma unroll
    for (int j = 0; j < 4; ++j) {
      const int f = kh * 1024 + k0 + j;
      const float fv = fs[j];
      float4 a4 = *(const float4*)(awp + (size_t)f * 4);
      float4 b4 = *(const float4*)(bbp + (size_t)f * 4);
      acc[0] += fv * a4.x; acc[1] += fv * a4.y; acc[2] += fv * a4.z; acc[3] += fv * a4.w;
      acc[4] += fv * b4.x; acc[5] += fv * b4.y; acc[6] += fv * b4.z; acc[7] += fv * b4.w;
      const float* cr = cwp + (size_t)f * 21;
#pragma unroll
      for (int c = 0; c < 21; ++c) acc[8 + c] += fv * cr[c];
      acc[29] += fv * awcp[f];
    }
  }

  __shared__ float red[128][30];
  if (kh == 1) {
#pragma unroll
    for (int i = 0; i < 30; ++i) red[r][i] = acc[i];
  }
  __syncthreads();
  if (kh == 0) {
#pragma unroll
    for (int i = 0; i < 30; ++i) acc[i] += red[r][i];
    float* o = smallf + ((size_t)a * NN + row) * 32;
#pragma unroll
    for (int i = 0; i < 30; ++i) o[i] = acc[i];
    o[30] = 0.f; o[31] = 0.f;
    float* co = cls_out + ((size_t)a * NN + row) * 21;
#pragma unroll
    for (int c = 0; c < 21; ++c) co[c] = acc[8 + c];
  }
}

// ---------------- bf16 MFMA GEMM: C[M,N] = A[M,K] * Bt[N,K]^T ----------------
// AF32: A is f32 (features; batch 9 reads A2v = gt_features), converted during staging
template<int BM, int BN, int WM, int WN, bool AF32, bool RELU, bool OUTBF>
__global__ __launch_bounds__(WM * WN * 64)
void gemm_bt(const void* __restrict__ Av, const void* __restrict__ A2v, long sA,
             const u16* __restrict__ B, long sB,
             void* __restrict__ Cv, long sC,
             int N, int K) {
  constexpr int THREADS = WM * WN * 64;
  constexpr int WTM = BM / WM, WTN = BN / WN;
  constexpr int FM = WTM / 16, FN = WTN / 16;
  constexpr int ACH = (BM * 4) / THREADS;          // 16B bf16 chunks per thread for A
  constexpr int BCHN = BN * 4;
  constexpr int BCH = (BCHN + THREADS - 1) / THREADS;
  constexpr bool BFULL = (BCHN % THREADS) == 0;

  __shared__ __align__(16) u16 As[BM * 32];
  __shared__ __align__(16) u16 Bs[BN * 32];

  const int tid = threadIdx.x;
  const int lane = tid & 63, wave = tid >> 6;
  const int wm = wave % WM, wn = wave / WM;
  const int tileN = blockIdx.x * BN, tileM = blockIdx.y * BM;
  const int batch = blockIdx.z;

  const u16* Ab16 = nullptr;
  const float* Ab32 = nullptr;
  if constexpr (AF32) {
    const float* base = (batch < 9) ? ((const float*)Av + (size_t)batch * sA)
                                    : (const float*)A2v;
    Ab32 = base + (size_t)tileM * K;
  } else {
    Ab16 = (const u16*)Av + (size_t)batch * sA + (size_t)tileM * K;
  }
  const u16* Bb = B + (size_t)batch * sB + (size_t)tileN * K;

  f32x4 acc[FM][FN];
#pragma unroll
  for (int i = 0; i < FM; ++i)
#pragma unroll
    for (int j = 0; j < FN; ++j) acc[i][j] = (f32x4){0.f, 0.f, 0.f, 0.f};

  uint4 ra[ACH], rb[BCH];
  auto load_t = [&](int k0) {
#pragma unroll
    for (int i = 0; i < ACH; ++i) {
      int c = tid + i * THREADS;
      if constexpr (AF32) {
        const float* s = Ab32 + (size_t)(c >> 2) * K + k0 + (c & 3) * 8;
        float4 u = *(const float4*)s;
        float4 v = *(const float4*)(s + 4);
        ra[i] = pack8(u, v);
      } else {
        ra[i] = *(const uint4*)(Ab16 + (size_t)(c >> 2) * K + k0 + (c & 3) * 8);
      }
    }
#pragma unroll
    for (int i = 0; i < BCH; ++i) {
      int c = tid + i * THREADS;
      if (BFULL || c < BCHN)
        rb[i] = *(const uint4*)(Bb + (size_t)(c >> 2) * K + k0 + (c & 3) * 8);
    }
  };

  load_t(0);
  const u16* Arow = As + (wm * WTM + (lane & 15)) * 32 + (lane >> 4) * 8;
  const u16* Brow = Bs + (wn * WTN + (lane & 15)) * 32 + (lane >> 4) * 8;

  for (int k0 = 0; k0 < K; k0 += 32) {
    __syncthreads();
#pragma unroll
    for (int i = 0; i < ACH; ++i)
      *(uint4*)(As + (size_t)(tid + i * THREADS) * 8) = ra[i];
#pragma unroll
    for (int i = 0; i < BCH; ++i) {
      int c = tid + i * THREADS;
      if (BFULL || c < BCHN) *(uint4*)(Bs + (size_t)c * 8) = rb[i];
    }
    __syncthreads();
    if (k0 + 32 < K) load_t(k0 + 32);   // prefetch next tile under MFMA

    s16x8 af[FM], bfr[FN];
#pragma unroll
    for (int i = 0; i < FM; ++i) af[i] = *(const s16x8*)(Arow + i * 16 * 32);
#pragma unroll
    for (int j = 0; j < FN; ++j) bfr[j] = *(const s16x8*)(Brow + j * 16 * 32);
#pragma unroll
    for (int i = 0; i < FM; ++i)
#pragma unroll
      for (int j = 0; j < FN; ++j)
        acc[i][j] = __builtin_amdgcn_mfma_f32_16x16x32_bf16(af[i], bfr[j], acc[i][j], 0, 0, 0);
  }

  const int r0 = tileM + wm * WTM + (lane >> 4) * 4;
  const int c0 = tileN + wn * WTN + (lane & 15);
#pragma unroll
  for (int i = 0; i < FM; ++i)
#pragma unroll
    for (int j = 0; j < FN; ++j)
#pragma unroll
      for (int q = 0; q < 4; ++q) {
        float v = acc[i][j][q];
        if (RELU) v = fmaxf(v, 0.f);
        size_t idx = (size_t)batch * sC + (size_t)(r0 + i * 16 + q) * N + (c0 + j * 16);
        if (OUTBF) ((u16*)Cv)[idx] = f2b(v);
        else       ((float*)Cv)[idx] = v;
      }
}

// ---------------- beta = scale * sum_k q*key - iou, wave per n ----------------
__global__ __launch_bounds__(64) void beta_kernel(const float* __restrict__ qk,
                                                  const float* __restrict__ ious,
                                                  float* __restrict__ beta,
                                                  float* __restrict__ betac) {
  int n = blockIdx.x;
  int l = threadIdx.x;
  const float* key = qk + (size_t)9 * NN * QCOLS + (size_t)n * QCOLS;
  float k0 = key[l], k1 = key[64 + l];
  float k2 = (l < 32) ? key[128 + l] : 0.f;
  const float scale = 0.17677669529663687f;  // 1/sqrt(32)
  for (int a = 0; a < 9; ++a) {
    const float* q = qk + ((size_t)a * NN + n) * QCOLS;
    float pm = q[l] * k0 + q[64 + l] * k1;
    float pc = (l < 32) ? q[128 + l] * k2 : 0.f;
#pragma unroll
    for (int m = 4; m < 64; m <<= 1) pm += __shfl_xor(pm, m);
#pragma unroll
    for (int m = 1; m < 64; m <<= 1) pc += __shfl_xor(pc, m);
    float iou = ious[(size_t)a * NN + n];
    if (l < 4) beta[((size_t)a * NN + n) * 4 + l] = pm * scale - iou;
    if (l == 0) betac[(size_t)a * NN + n] = pc * scale - iou;
  }
}

// ---------------- softmaxes + outputs (all f32), thread per n ----------------
__global__ __launch_bounds__(256) void finalize(const float* __restrict__ smallf,
                                                const float* __restrict__ beta_ws,
                                                const float* __restrict__ betac_ws,
                                                const float* __restrict__ delta_rois,
                                                float* __restrict__ out) {
  int n = blockIdx.x * blockDim.x + threadIdx.x;
  if (n >= NN) return;

  for (int c = 0; c < 4; ++c) {
    float al[9], be[9], dp[9];
    float mA = -1e30f, mB = -1e30f;
    for (int a = 0; a < 9; ++a) {
      size_t an = (size_t)a * NN + n;
      al[a] = smallf[an * 32 + c];
      float off_ = smallf[an * 32 + 4 + c];
      dp[a] = delta_rois[an * 5 + 1 + c] + off_;
      be[a] = beta_ws[an * 4 + c];
      mA = fmaxf(mA, al[a]); mB = fmaxf(mB, be[a]);
    }
    float eA[9], eB[9], sA = 0.f, sB = 0.f;
    for (int a = 0; a < 9; ++a) {
      eA[a] = expf(al[a] - mA); sA += eA[a];
      eB[a] = expf(be[a] - mB); sB += eB[a];
    }
    float rA = 1.f / sA, rB = 1.f / sB;
    float ov = 0.f, obv = 0.f;
    for (int a = 0; a < 9; ++a) {
      size_t an = (size_t)a * NN + n;
      float as_ = eA[a] * rA, bs_ = eB[a] * rB;
      out[O2 + an * 4 + c] = as_;
      out[O3 + an * 4 + c] = bs_;
      out[O4 + an * 4 + c] = dp[a];
      out[O5 + an * 4 + c] = dp[a];
      out[O6 + an * 4 + c] = al[a];
      out[O7 + an * 4 + c] = be[a];
      ov += dp[a] * as_; obv += dp[a] * bs_;
    }
    out[O0 + (size_t)n * 4 + c] = ov;
    out[O1 + (size_t)n * 4 + c] = obv;
  }

  // cls branch
  float ac[9], bc[9];
  float mA = -1e30f, mB = -1e30f;
  for (int a = 0; a < 9; ++a) {
    size_t an = (size_t)a * NN + n;
    ac[a] = smallf[an * 32 + 29];
    bc[a] = betac_ws[an];
    mA = fmaxf(mA, ac[a]); mB = fmaxf(mB, bc[a]);
  }
  float eA[9], eB[9], sA = 0.f, sB = 0.f;
  for (int a = 0; a < 9; ++a) {
    eA[a] = expf(ac[a] - mA); sA += eA[a];
    eB[a] = expf(bc[a] - mB); sB += eB[a];
  }
  float rA = 1.f / sA, rB = 1.f / sB;
  for (int a = 0; a < 9; ++a) {
    size_t an = (size_t)a * NN + n;
    out[O9 + an]  = eA[a] * rA;
    out[O10 + an] = eB[a] * rB;
    out[O11 + an] = ac[a];
    out[O12 + an] = bc[a];
  }
}

extern "C" void kernel_launch(void* const* d_in, const int* in_sizes, int n_in,
                              void* d_out, int out_size, void* d_ws, size_t ws_size,
                              hipStream_t stream) {
  const float* delta_rois = (const float*)d_in[1];
  const float* features   = (const float*)d_in[2];
  const float* gt_features= (const float*)d_in[3];
  const float* ious       = (const float*)d_in[4];
  const float* att        = (const float*)d_in[5];
  const float* w_k        = (const float*)d_in[6];
  const float* w_q        = (const float*)d_in[7];
  const float* alpha_w    = (const float*)d_in[8];
  const float* bbox       = (const float*)d_in[9];
  const float* w_k_cls    = (const float*)d_in[10];
  const float* w_q_cls    = (const float*)d_in[11];
  const float* alpha_w_cls= (const float*)d_in[12];
  const float* cls_w      = (const float*)d_in[13];
  float* out = (float*)d_out;

  char* ws = (char*)d_ws;
  u16* attB    = (u16*)ws;   ws += (size_t)DAPP * DORI * 2;      // 2.1 MB
  u16* Wq      = (u16*)ws;   ws += (size_t)NB * QCOLS * DAPP * 2;// 1.6 MB
  u16* offb    = (u16*)ws;   ws += (size_t)NB * NN * DAPP * 2;   // 42 MB (batch9 = gt_off)
  float* smallf= (float*)ws; ws += (size_t)AN * NN * 32 * 4;     // 4.7 MB
  float* qkf   = (float*)ws; ws += (size_t)NB * NN * QCOLS * 4;  // 26.2 MB (batch9 = key)
  float* betaf = (float*)ws; ws += (size_t)AN * NN * 4 * 4;      // 2.4 MB
  float* betac = (float*)ws; ws += (size_t)AN * NN * 4;          // 0.15 MB
  // total ~79 MB

  transpose_att<<<(DAPP * DORI + 255) / 256, 256, 0, stream>>>(att, attB);
  pack_q<<<(NB * QCOLS * DAPP + 255) / 256, 256, 0, stream>>>(w_q, w_q_cls, w_k, w_k_cls, Wq);

  dim3 gs(AN, NN / 128, 1);
  small_valu<<<gs, 256, 0, stream>>>(features, alpha_w, bbox, cls_w, alpha_w_cls,
                                     smallf, out + O8);

  // off = relu(features @ attention_feat)  [10 batches, batch9 = gt]
  dim3 g1(DAPP / 128, NN / 128, NB);
  gemm_bt<128, 128, 2, 2, true, true, true><<<g1, 256, 0, stream>>>(
      features, gt_features, (long)NN * DORI, attB, 0, offb, (long)NN * DAPP, DAPP, DORI);

  // qk = off @ Wq^T  [10 batches, batch9 = key from gt_off]
  dim3 g3(QCOLS / 32, NN / 128, NB);
  gemm_bt<128, 32, 4, 1, false, false, false><<<g3, 256, 0, stream>>>(
      offb, nullptr, (long)NN * DAPP, Wq, (long)QCOLS * DAPP, qkf, (long)NN * QCOLS, QCOLS, DAPP);

  beta_kernel<<<NN, 64, 0, stream>>>(qkf, ious, betaf, betac);
  finalize<<<NN / 256, 256, 0, stream>>>(smallf, betaf, betac, delta_rois, out);
}

// Round 4
// 369.481 us; speedup vs baseline: 2.6843x; 2.6843x over previous
//
#include <hip/hip_runtime.h>

using u16 = unsigned short;
using s16x8 = __attribute__((ext_vector_type(8))) short;   // 8 bf16 (4 VGPRs)
using f32x4 = __attribute__((ext_vector_type(4))) float;

#define DEVI __device__ __forceinline__

constexpr int AN = 9, NB = 10, NN = 4096, DORI = 2048, DAPP = 512, NCLS = 21, QCOLS = 160;

// output offsets (f32 elements) in return order
constexpr size_t O0 = 0;                 // output            (4096,4)
constexpr size_t O1 = 16384;             // output_beta       (4096,4)
constexpr size_t O2 = 32768;             // alpha_softmax     (9,4096,4)
constexpr size_t O3 = 180224;            // beta_softmax      (9,4096,4)
constexpr size_t O4 = 327680;            // delta_pred_offset (9,4096,4)
constexpr size_t O5 = 475136;            // delta_pred_offset (9,4096,4)
constexpr size_t O6 = 622592;            // alpha             (9,4096,4)
constexpr size_t O7 = 770048;            // beta_out          (9,4096,4)
constexpr size_t O8 = 917504;            // cls_score         (9,4096,21)
constexpr size_t O9 = 1691648;           // alpha_softmax_cls (9,4096,1)
constexpr size_t O10 = 1728512;          // beta_softmax_cls
constexpr size_t O11 = 1765376;          // alpha_cls
constexpr size_t O12 = 1802240;          // beta_out_cls

DEVI u16 f2b(float f) {                   // f32 -> bf16 RNE (internal use only)
  unsigned u = __float_as_uint(f);
  unsigned r = (u + 0x7fffu + ((u >> 16) & 1u)) >> 16;
  return (u16)r;
}

DEVI uint4 pack8(float4 u, float4 v) {    // 8 f32 -> 8 bf16 packed
  uint4 r;
  r.x = (unsigned)f2b(u.x) | ((unsigned)f2b(u.y) << 16);
  r.y = (unsigned)f2b(u.z) | ((unsigned)f2b(u.w) << 16);
  r.z = (unsigned)f2b(v.x) | ((unsigned)f2b(v.y) << 16);
  r.w = (unsigned)f2b(v.z) | ((unsigned)f2b(v.w) << 16);
  return r;
}

DEVI void gload_lds16(const u16* g, u16* l) {   // 16B global -> LDS direct
  __builtin_amdgcn_global_load_lds(
      (const __attribute__((address_space(1))) void*)g,
      (__attribute__((address_space(3))) void*)l, 16, 0, 0);
}

// ---------------- generic f32 -> bf16 cast, 8 elems/thread ----------------
__global__ __launch_bounds__(256) void cast_kernel(const float* __restrict__ src,
                                                   u16* __restrict__ dst, long n8) {
  long i = (long)blockIdx.x * blockDim.x + threadIdx.x;
  long stride = (long)gridDim.x * blockDim.x;
  for (; i < n8; i += stride) {
    float4 v0 = ((const float4*)src)[i * 2];
    float4 v1 = ((const float4*)src)[i * 2 + 1];
    ((uint4*)dst)[i] = pack8(v0, v1);
  }
}

// ---------------- attention_feat (2048,512) -> attB (512,2048) bf16 ----------------
__global__ __launch_bounds__(256) void transpose_att(const float* __restrict__ in,
                                                     u16* __restrict__ out) {
  int t = blockIdx.x * blockDim.x + threadIdx.x;
  if (t >= DAPP * DORI) return;
  int c = t / DORI, d = t % DORI;
  out[t] = f2b(in[d * DAPP + c]);
}

// ---------------- pack small weights: Wsmall[a][32][2048] bf16 ----------------
// cols 0-3 alpha_w, 4-7 bbox_regress, 8-28 cls_score_w, 29 alpha_w_cls, 30-31 zero
__global__ __launch_bounds__(256) void pack_small(const float* __restrict__ aw,
                                                  const float* __restrict__ bb,
                                                  const float* __restrict__ awc,
                                                  const float* __restrict__ cw,
                                                  u16* __restrict__ W) {
  int t = blockIdx.x * blockDim.x + threadIdx.x;
  if (t >= AN * DORI) return;
  int a = t / DORI, f = t % DORI;
  u16* Wa = W + (size_t)a * 32 * DORI;
  for (int c = 0; c < 4; ++c)  Wa[c * DORI + f]       = f2b(aw[((size_t)a * DORI + f) * 4 + c]);
  for (int c = 0; c < 4; ++c)  Wa[(4 + c) * DORI + f] = f2b(bb[((size_t)a * DORI + f) * 4 + c]);
  for (int c = 0; c < 21; ++c) Wa[(8 + c) * DORI + f] = f2b(cw[((size_t)a * DORI + f) * 21 + c]);
  Wa[29 * DORI + f] = f2b(awc[(size_t)a * DORI + f]);
  Wa[30 * DORI + f] = 0;
  Wa[31 * DORI + f] = 0;
}

// ---------------- pack query/key weights: Wq[b][160][512] bf16 ----------------
__global__ __launch_bounds__(256) void pack_q(const float* __restrict__ wq,
                                              const float* __restrict__ wqc,
                                              const float* __restrict__ wk,
                                              const float* __restrict__ wkc,
                                              u16* __restrict__ W) {
  int t = blockIdx.x * blockDim.x + threadIdx.x;
  if (t >= NB * QCOLS * DAPP) return;
  int b = t / (QCOLS * DAPP);
  int r = t % (QCOLS * DAPP);
  int col = r / DAPP, d = r % DAPP;
  float v;
  if (b < 9) {
    if (col < 128) v = wq[(size_t)b * DAPP * 128 + (size_t)d * 128 + col];
    else           v = wqc[(size_t)b * DAPP * 32 + (size_t)d * 32 + (col - 128)];
  } else {
    if (col < 128) v = wk[(size_t)d * 128 + col];
    else           v = wkc[(size_t)d * 32 + (col - 128)];
  }
  W[t] = f2b(v);
}

// ---------------- feat_gemm: smallf = features @ Wsmall^T, fused bf16 cast-writeback ----
// BM=64, BN=32, 256 threads (4 waves on M), reads f32 features ONCE, optional featB write
__global__ __launch_bounds__(256) void feat_gemm(const float* __restrict__ feat,
                                                 const u16* __restrict__ Wsm,
                                                 float* __restrict__ smallf,
                                                 u16* __restrict__ wb) {
  __shared__ __align__(16) u16 As[64 * 32];
  __shared__ __align__(16) u16 Bs[32 * 32];
  const int tid = threadIdx.x, lane = tid & 63, wave = tid >> 6;
  const int tileM = blockIdx.y * 64, batch = blockIdx.z;
  const float* Ab = feat + ((size_t)batch * NN + tileM) * DORI;
  const u16* Bb = Wsm + (size_t)batch * 32 * DORI;
  u16* wbp = wb ? wb + ((size_t)batch * NN + tileM) * DORI : nullptr;

  f32x4 acc0 = {0.f, 0.f, 0.f, 0.f}, acc1 = {0.f, 0.f, 0.f, 0.f};
  const int arow = tid >> 2, acol = (tid & 3) * 8;
  const bool bact = tid < 128;
  uint4 ra, rbv;
  auto load_t = [&](int k0) {
    const float* s = Ab + (size_t)arow * DORI + k0 + acol;
    float4 u = *(const float4*)s, v = *(const float4*)(s + 4);
    ra = pack8(u, v);
    if (bact) rbv = *(const uint4*)(Bb + (size_t)arow * DORI + k0 + acol);
  };
  load_t(0);
  const u16* Arow = As + (wave * 16 + (lane & 15)) * 32 + (lane >> 4) * 8;
  const u16* Brow = Bs + (lane & 15) * 32 + (lane >> 4) * 8;

  for (int k0 = 0; k0 < DORI; k0 += 32) {
    __syncthreads();
    *(uint4*)(As + (size_t)tid * 8) = ra;
    if (bact) *(uint4*)(Bs + (size_t)tid * 8) = rbv;
    if (wbp) *(uint4*)(wbp + (size_t)arow * DORI + k0 + acol) = ra;
    __syncthreads();
    if (k0 + 32 < DORI) load_t(k0 + 32);
    s16x8 af = *(const s16x8*)Arow;
    s16x8 b0 = *(const s16x8*)Brow;
    s16x8 b1 = *(const s16x8*)(Brow + 16 * 32);
    acc0 = __builtin_amdgcn_mfma_f32_16x16x32_bf16(af, b0, acc0, 0, 0, 0);
    acc1 = __builtin_amdgcn_mfma_f32_16x16x32_bf16(af, b1, acc1, 0, 0, 0);
  }

  const int r0 = tileM + wave * 16 + (lane >> 4) * 4;
  const int c0 = lane & 15;
#pragma unroll
  for (int q = 0; q < 4; ++q) {
    smallf[((size_t)batch * NN + r0 + q) * 32 + c0]      = acc0[q];
    smallf[((size_t)batch * NN + r0 + q) * 32 + c0 + 16] = acc1[q];
  }
}

// ---------------- bf16 GEMM with global_load_lds staging ----------------
// C[M,N] = A[M,K] * Bt[N,K]^T ; all bf16 operands
template<int BM, int BN, int WM, int WN, bool RELU, bool OUTBF, bool SWZ>
__global__ __launch_bounds__(WM * WN * 64)
void gemm_glds(const u16* __restrict__ A, long sA, const u16* __restrict__ B, long sB,
               void* __restrict__ Cv, long sC, int N, int K) {
  constexpr int THREADS = WM * WN * 64;
  constexpr int WTM = BM / WM, WTN = BN / WN;
  constexpr int FM = WTM / 16, FN = WTN / 16;
  constexpr int ACHN = BM * 4, BCHN = BN * 4;
  constexpr int ACH = (ACHN + THREADS - 1) / THREADS;
  constexpr int BCH = (BCHN + THREADS - 1) / THREADS;
  constexpr bool AFULL = (ACHN % THREADS) == 0, BFULL = (BCHN % THREADS) == 0;

  __shared__ __align__(16) u16 As[BM * 32];
  __shared__ __align__(16) u16 Bs[BN * 32];

  int bx = blockIdx.x, by = blockIdx.y, bz = blockIdx.z;
  if constexpr (SWZ) {   // chunked XCD swizzle (nwg % 8 == 0 required)
    int gx = gridDim.x, gy = gridDim.y;
    int h = bx + gx * (by + gy * bz);
    int nwg = gx * gy * (int)gridDim.z;
    int cpx = nwg >> 3;
    int l = (h & 7) * cpx + (h >> 3);
    bx = l % gx; l /= gx; by = l % gy; bz = l / gy;
  }

  const int tid = threadIdx.x, lane = tid & 63, wave = tid >> 6;
  const int wm = wave % WM, wn = wave / WM;
  const int tileN = bx * BN, tileM = by * BM;
  const u16* Ab = A + (size_t)bz * sA + (size_t)tileM * K;
  const u16* Bb = B + (size_t)bz * sB + (size_t)tileN * K;

  f32x4 acc[FM][FN];
#pragma unroll
  for (int i = 0; i < FM; ++i)
#pragma unroll
    for (int j = 0; j < FN; ++j) acc[i][j] = (f32x4){0.f, 0.f, 0.f, 0.f};

  const u16* Arow = As + (wm * WTM + (lane & 15)) * 32 + (lane >> 4) * 8;
  const u16* Brow = Bs + (wn * WTN + (lane & 15)) * 32 + (lane >> 4) * 8;

  for (int k0 = 0; k0 < K; k0 += 32) {
#pragma unroll
    for (int i = 0; i < ACH; ++i) {
      int c = tid + i * THREADS;
      if (AFULL || c < ACHN)
        gload_lds16(Ab + (size_t)(c >> 2) * K + k0 + (c & 3) * 8, As + c * 8);
    }
#pragma unroll
    for (int i = 0; i < BCH; ++i) {
      int c = tid + i * THREADS;
      if (BFULL || c < BCHN)
        gload_lds16(Bb + (size_t)(c >> 2) * K + k0 + (c & 3) * 8, Bs + c * 8);
    }
    __syncthreads();          // compiler drains vmcnt before barrier -> tile ready
    s16x8 af[FM], bfr[FN];
#pragma unroll
    for (int i = 0; i < FM; ++i) af[i] = *(const s16x8*)(Arow + i * 16 * 32);
#pragma unroll
    for (int j = 0; j < FN; ++j) bfr[j] = *(const s16x8*)(Brow + j * 16 * 32);
#pragma unroll
    for (int i = 0; i < FM; ++i)
#pragma unroll
      for (int j = 0; j < FN; ++j)
        acc[i][j] = __builtin_amdgcn_mfma_f32_16x16x32_bf16(af[i], bfr[j], acc[i][j], 0, 0, 0);
    __syncthreads();          // reads done before next stage overwrites
  }

  const int r0 = tileM + wm * WTM + (lane >> 4) * 4;
  const int c0 = tileN + wn * WTN + (lane & 15);
#pragma unroll
  for (int i = 0; i < FM; ++i)
#pragma unroll
    for (int j = 0; j < FN; ++j)
#pragma unroll
      for (int q = 0; q < 4; ++q) {
        float v = acc[i][j][q];
        if (RELU) v = fmaxf(v, 0.f);
        size_t idx = (size_t)bz * sC + (size_t)(r0 + i * 16 + q) * N + (c0 + j * 16);
        if (OUTBF) ((u16*)Cv)[idx] = f2b(v);
        else       ((float*)Cv)[idx] = v;
      }
}

// ---------------- fallback gemm (A = f32, reg-staged pack) -- small-ws mode ----------------
template<int BM, int BN, int WM, int WN, bool RELU, bool OUTBF>
__global__ __launch_bounds__(WM * WN * 64)
void gemm_af32(const float* __restrict__ Av, const float* __restrict__ A2v, long sA,
               const u16* __restrict__ B, long sB,
               void* __restrict__ Cv, long sC, int N, int K) {
  constexpr int THREADS = WM * WN * 64;
  constexpr int WTM = BM / WM, WTN = BN / WN;
  constexpr int FM = WTM / 16, FN = WTN / 16;
  constexpr int ACH = (BM * 4) / THREADS;
  constexpr int BCHN = BN * 4;
  constexpr int BCH = (BCHN + THREADS - 1) / THREADS;
  constexpr bool BFULL = (BCHN % THREADS) == 0;

  __shared__ __align__(16) u16 As[BM * 32];
  __shared__ __align__(16) u16 Bs[BN * 32];

  const int tid = threadIdx.x, lane = tid & 63, wave = tid >> 6;
  const int wm = wave % WM, wn = wave / WM;
  const int tileN = blockIdx.x * BN, tileM = blockIdx.y * BM;
  const int batch = blockIdx.z;
  const float* base = (batch < 9) ? (Av + (size_t)batch * sA) : A2v;
  const float* Ab32 = base + (size_t)tileM * K;
  const u16* Bb = B + (size_t)batch * sB + (size_t)tileN * K;

  f32x4 acc[FM][FN];
#pragma unroll
  for (int i = 0; i < FM; ++i)
#pragma unroll
    for (int j = 0; j < FN; ++j) acc[i][j] = (f32x4){0.f, 0.f, 0.f, 0.f};

  uint4 ra[ACH], rb[BCH];
  auto load_t = [&](int k0) {
#pragma unroll
    for (int i = 0; i < ACH; ++i) {
      int c = tid + i * THREADS;
      const float* s = Ab32 + (size_t)(c >> 2) * K + k0 + (c & 3) * 8;
      ra[i] = pack8(*(const float4*)s, *(const float4*)(s + 4));
    }
#pragma unroll
    for (int i = 0; i < BCH; ++i) {
      int c = tid + i * THREADS;
      if (BFULL || c < BCHN)
        rb[i] = *(const uint4*)(Bb + (size_t)(c >> 2) * K + k0 + (c & 3) * 8);
    }
  };

  load_t(0);
  const u16* Arow = As + (wm * WTM + (lane & 15)) * 32 + (lane >> 4) * 8;
  const u16* Brow = Bs + (wn * WTN + (lane & 15)) * 32 + (lane >> 4) * 8;

  for (int k0 = 0; k0 < K; k0 += 32) {
    __syncthreads();
#pragma unroll
    for (int i = 0; i < ACH; ++i)
      *(uint4*)(As + (size_t)(tid + i * THREADS) * 8) = ra[i];
#pragma unroll
    for (int i = 0; i < BCH; ++i) {
      int c = tid + i * THREADS;
      if (BFULL || c < BCHN) *(uint4*)(Bs + (size_t)c * 8) = rb[i];
    }
    __syncthreads();
    if (k0 + 32 < K) load_t(k0 + 32);
    s16x8 af[FM], bfr[FN];
#pragma unroll
    for (int i = 0; i < FM; ++i) af[i] = *(const s16x8*)(Arow + i * 16 * 32);
#pragma unroll
    for (int j = 0; j < FN; ++j) bfr[j] = *(const s16x8*)(Brow + j * 16 * 32);
#pragma unroll
    for (int i = 0; i < FM; ++i)
#pragma unroll
      for (int j = 0; j < FN; ++j)
        acc[i][j] = __builtin_amdgcn_mfma_f32_16x16x32_bf16(af[i], bfr[j], acc[i][j], 0, 0, 0);
  }

  const int r0 = tileM + wm * WTM + (lane >> 4) * 4;
  const int c0 = tileN + wn * WTN + (lane & 15);
#pragma unroll
  for (int i = 0; i < FM; ++i)
#pragma unroll
    for (int j = 0; j < FN; ++j)
#pragma unroll
      for (int q = 0; q < 4; ++q) {
        float v = acc[i][j][q];
        if (RELU) v = fmaxf(v, 0.f);
        size_t idx = (size_t)batch * sC + (size_t)(r0 + i * 16 + q) * N + (c0 + j * 16);
        if (OUTBF) ((u16*)Cv)[idx] = f2b(v);
        else       ((float*)Cv)[idx] = v;
      }
}

// ---------------- beta = scale * sum_k q*key - iou, wave per n ----------------
__global__ __launch_bounds__(64) void beta_kernel(const float* __restrict__ qk,
                                                  const float* __restrict__ ious,
                                                  float* __restrict__ beta,
                                                  float* __restrict__ betac) {
  int n = blockIdx.x;
  int l = threadIdx.x;
  const float* key = qk + (size_t)9 * NN * QCOLS + (size_t)n * QCOLS;
  float k0 = key[l], k1 = key[64 + l];
  float k2 = (l < 32) ? key[128 + l] : 0.f;
  const float scale = 0.17677669529663687f;  // 1/sqrt(32)
  for (int a = 0; a < 9; ++a) {
    const float* q = qk + ((size_t)a * NN + n) * QCOLS;
    float pm = q[l] * k0 + q[64 + l] * k1;
    float pc = (l < 32) ? q[128 + l] * k2 : 0.f;
#pragma unroll
    for (int m = 4; m < 64; m <<= 1) pm += __shfl_xor(pm, m);
#pragma unroll
    for (int m = 1; m < 64; m <<= 1) pc += __shfl_xor(pc, m);
    float iou = ious[(size_t)a * NN + n];
    if (l < 4) beta[((size_t)a * NN + n) * 4 + l] = pm * scale - iou;
    if (l == 0) betac[(size_t)a * NN + n] = pc * scale - iou;
  }
}

// ---------------- cls_score copy-out (f32) ----------------
__global__ __launch_bounds__(256) void cls_copy(const float* __restrict__ smallf,
                                                float* __restrict__ o) {
  int i = blockIdx.x * blockDim.x + threadIdx.x;
  if (i >= AN * NN * NCLS) return;
  int an = i / NCLS, c = i % NCLS;
  o[i] = smallf[(size_t)an * 32 + 8 + c];
}

// ---------------- softmaxes + outputs (all f32), thread per n ----------------
__global__ __launch_bounds__(256) void finalize(const float* __restrict__ smallf,
                                                const float* __restrict__ beta_ws,
                                                const float* __restrict__ betac_ws,
                                                const float* __restrict__ delta_rois,
                                                float* __restrict__ out) {
  int n = blockIdx.x * blockDim.x + threadIdx.x;
  if (n >= NN) return;

  for (int c = 0; c < 4; ++c) {
    float al[9], be[9], dp[9];
    float mA = -1e30f, mB = -1e30f;
    for (int a = 0; a < 9; ++a) {
      size_t an = (size_t)a * NN + n;
      al[a] = smallf[an * 32 + c];
      float off_ = smallf[an * 32 + 4 + c];
      dp[a] = delta_rois[an * 5 + 1 + c] + off_;
      be[a] = beta_ws[an * 4 + c];
      mA = fmaxf(mA, al[a]); mB = fmaxf(mB, be[a]);
    }
    float eA[9], eB[9], sA = 0.f, sB = 0.f;
    for (int a = 0; a < 9; ++a) {
      eA[a] = expf(al[a] - mA); sA += eA[a];
      eB[a] = expf(be[a] - mB); sB += eB[a];
    }
    float rA = 1.f / sA, rB = 1.f / sB;
    float ov = 0.f, obv = 0.f;
    for (int a = 0; a < 9; ++a) {
      size_t an = (size_t)a * NN + n;
      float as_ = eA[a] * rA, bs_ = eB[a] * rB;
      out[O2 + an * 4 + c] = as_;
      out[O3 + an * 4 + c] = bs_;
      out[O4 + an * 4 + c] = dp[a];
      out[O5 + an * 4 + c] = dp[a];
      out[O6 + an * 4 + c] = al[a];
      out[O7 + an * 4 + c] = be[a];
      ov += dp[a] * as_; obv += dp[a] * bs_;
    }
    out[O0 + (size_t)n * 4 + c] = ov;
    out[O1 + (size_t)n * 4 + c] = obv;
  }

  float ac[9], bc[9];
  float mA = -1e30f, mB = -1e30f;
  for (int a = 0; a < 9; ++a) {
    size_t an = (size_t)a * NN + n;
    ac[a] = smallf[an * 32 + 29];
    bc[a] = betac_ws[an];
    mA = fmaxf(mA, ac[a]); mB = fmaxf(mB, bc[a]);
  }
  float eA[9], eB[9], sA = 0.f, sB = 0.f;
  for (int a = 0; a < 9; ++a) {
    eA[a] = expf(ac[a] - mA); sA += eA[a];
    eB[a] = expf(bc[a] - mB); sB += eB[a];
  }
  float rA = 1.f / sA, rB = 1.f / sB;
  for (int a = 0; a < 9; ++a) {
    size_t an = (size_t)a * NN + n;
    out[O9 + an]  = eA[a] * rA;
    out[O10 + an] = eB[a] * rB;
    out[O11 + an] = ac[a];
    out[O12 + an] = bc[a];
  }
}

extern "C" void kernel_launch(void* const* d_in, const int* in_sizes, int n_in,
                              void* d_out, int out_size, void* d_ws, size_t ws_size,
                              hipStream_t stream) {
  const float* delta_rois = (const float*)d_in[1];
  const float* features   = (const float*)d_in[2];
  const float* gt_features= (const float*)d_in[3];
  const float* ious       = (const float*)d_in[4];
  const float* att        = (const float*)d_in[5];
  const float* w_k        = (const float*)d_in[6];
  const float* w_q        = (const float*)d_in[7];
  const float* alpha_w    = (const float*)d_in[8];
  const float* bbox       = (const float*)d_in[9];
  const float* w_k_cls    = (const float*)d_in[10];
  const float* w_q_cls    = (const float*)d_in[11];
  const float* alpha_w_cls= (const float*)d_in[12];
  const float* cls_w      = (const float*)d_in[13];
  float* out = (float*)d_out;

  char* ws = (char*)d_ws;
  u16* attB    = (u16*)ws;   ws += (size_t)DAPP * DORI * 2;       // 2.1 MB
  u16* Wq      = (u16*)ws;   ws += (size_t)NB * QCOLS * DAPP * 2; // 1.6 MB
  u16* Wsmall  = (u16*)ws;   ws += (size_t)AN * 32 * DORI * 2;    // 1.2 MB
  u16* offb    = (u16*)ws;   ws += (size_t)NB * NN * DAPP * 2;    // 42 MB (batch9 = gt_off)
  float* smallf= (float*)ws; ws += (size_t)AN * NN * 32 * 4;      // 4.7 MB
  float* qkf   = (float*)ws; ws += (size_t)NB * NN * QCOLS * 4;   // 26.2 MB (batch9 = key)
  float* betaf = (float*)ws; ws += (size_t)AN * NN * 4 * 4;       // 2.4 MB
  float* betac = (float*)ws; ws += (size_t)AN * NN * 4;           // 0.15 MB
  // base total ~80 MB; featB (+168 MB) only if workspace allows
  size_t base_bytes = (size_t)(ws - (char*)d_ws);
  size_t featB_bytes = (size_t)NB * NN * DORI * 2;
  bool big = ws_size >= base_bytes + featB_bytes;
  u16* featB = big ? (u16*)ws : nullptr;

  transpose_att<<<(DAPP * DORI + 255) / 256, 256, 0, stream>>>(att, attB);
  pack_q<<<(NB * QCOLS * DAPP + 255) / 256, 256, 0, stream>>>(w_q, w_q_cls, w_k, w_k_cls, Wq);
  pack_small<<<(AN * DORI + 255) / 256, 256, 0, stream>>>(alpha_w, bbox, alpha_w_cls, cls_w, Wsmall);

  // small path (alpha/offset/cls/alpha_cls) + fused features f32->bf16 writeback
  dim3 gf(1, NN / 64, AN);
  feat_gemm<<<gf, 256, 0, stream>>>(features, Wsmall, smallf, featB);

  if (big) {
    // gt_features -> featB batch 9
    cast_kernel<<<1024, 256, 0, stream>>>(gt_features, featB + (size_t)AN * NN * DORI,
                                          (long)NN * DORI / 8);
    // off = relu(featB @ attB^T): global_load_lds + XCD swizzle (nwg=1280, %8==0)
    dim3 g1(DAPP / 128, NN / 128, NB);
    gemm_glds<128, 128, 2, 2, true, true, true><<<g1, 256, 0, stream>>>(
        featB, (long)NN * DORI, attB, 0, offb, (long)NN * DAPP, DAPP, DORI);
  } else {
    dim3 g1(DAPP / 128, NN / 128, NB);
    gemm_af32<128, 128, 2, 2, true, true><<<g1, 256, 0, stream>>>(
        features, gt_features, (long)NN * DORI, attB, 0, offb, (long)NN * DAPP, DAPP, DORI);
  }

  // qk = off @ Wq^T  [10 batches, batch9 = key from gt_off]
  dim3 g3(QCOLS / 32, NN / 128, NB);
  gemm_glds<128, 32, 4, 1, false, false, false><<<g3, 256, 0, stream>>>(
      offb, (long)NN * DAPP, Wq, (long)QCOLS * DAPP, qkf, (long)NN * QCOLS, QCOLS, DAPP);

  beta_kernel<<<NN, 64, 0, stream>>>(qkf, ious, betaf, betac);
  cls_copy<<<(AN * NN * NCLS + 255) / 256, 256, 0, stream>>>(smallf, out + O8);
  finalize<<<NN / 256, 256, 0, stream>>>(smallf, betaf, betac, delta_rois, out);
}

// Round 5
// 340.058 us; speedup vs baseline: 2.9165x; 1.0865x over previous
//
#include <hip/hip_runtime.h>

using u16 = unsigned short;
using s16x8 = __attribute__((ext_vector_type(8))) short;   // 8 bf16 (4 VGPRs)
using f32x4 = __attribute__((ext_vector_type(4))) float;

#define DEVI __device__ __forceinline__

constexpr int AN = 9, NB = 10, NN = 4096, DORI = 2048, DAPP = 512, NCLS = 21, QCOLS = 160;

// output offsets (f32 elements) in return order
constexpr size_t O0 = 0;                 // output            (4096,4)
constexpr size_t O1 = 16384;             // output_beta       (4096,4)
constexpr size_t O2 = 32768;             // alpha_softmax     (9,4096,4)
constexpr size_t O3 = 180224;            // beta_softmax      (9,4096,4)
constexpr size_t O4 = 327680;            // delta_pred_offset (9,4096,4)
constexpr size_t O5 = 475136;            // delta_pred_offset (9,4096,4)
constexpr size_t O6 = 622592;            // alpha             (9,4096,4)
constexpr size_t O7 = 770048;            // beta_out          (9,4096,4)
constexpr size_t O8 = 917504;            // cls_score         (9,4096,21)
constexpr size_t O9 = 1691648;           // alpha_softmax_cls (9,4096,1)
constexpr size_t O10 = 1728512;          // beta_softmax_cls
constexpr size_t O11 = 1765376;          // alpha_cls
constexpr size_t O12 = 1802240;          // beta_out_cls

DEVI u16 f2b(float f) {                   // f32 -> bf16 RNE (internal use only)
  unsigned u = __float_as_uint(f);
  unsigned r = (u + 0x7fffu + ((u >> 16) & 1u)) >> 16;
  return (u16)r;
}

DEVI uint4 pack8(float4 u, float4 v) {    // 8 f32 -> 8 bf16 packed
  uint4 r;
  r.x = (unsigned)f2b(u.x) | ((unsigned)f2b(u.y) << 16);
  r.y = (unsigned)f2b(u.z) | ((unsigned)f2b(u.w) << 16);
  r.z = (unsigned)f2b(v.x) | ((unsigned)f2b(v.y) << 16);
  r.w = (unsigned)f2b(v.z) | ((unsigned)f2b(v.w) << 16);
  return r;
}

DEVI void gload_lds16(const u16* g, u16* l) {   // 16B global -> LDS direct
  __builtin_amdgcn_global_load_lds(
      (const __attribute__((address_space(1))) void*)g,
      (__attribute__((address_space(3))) void*)l, 16, 0, 0);
}

// ================= fused prep: transpose_att | pack_q | pack_small | cast gt =======
// block ranges: [0,4096) att, [4096,7296) pack_q, [7296,7368) pack_small, [7368,11464) cast
__global__ __launch_bounds__(256) void prep(const float* __restrict__ att,
                                            const float* __restrict__ wq,
                                            const float* __restrict__ wqc,
                                            const float* __restrict__ wk,
                                            const float* __restrict__ wkc,
                                            const float* __restrict__ aw,
                                            const float* __restrict__ bb,
                                            const float* __restrict__ awc,
                                            const float* __restrict__ cw,
                                            const float* __restrict__ gt,
                                            u16* __restrict__ attB,
                                            u16* __restrict__ Wq,
                                            u16* __restrict__ Wsm,
                                            u16* __restrict__ featB9) {
  const int b = blockIdx.x, tid = threadIdx.x;
  if (b < 4096) {                                   // attB[c][d] = att[d][c]
    int t = b * 256 + tid;
    int c = t / DORI, d = t % DORI;
    attB[t] = f2b(att[(size_t)d * DAPP + c]);
  } else if (b < 7296) {                            // Wq[b][160][512]
    int t = (b - 4096) * 256 + tid;
    int bq = t / (QCOLS * DAPP);
    int r = t % (QCOLS * DAPP);
    int col = r / DAPP, d = r % DAPP;
    float v;
    if (bq < 9) {
      if (col < 128) v = wq[(size_t)bq * DAPP * 128 + (size_t)d * 128 + col];
      else           v = wqc[(size_t)bq * DAPP * 32 + (size_t)d * 32 + (col - 128)];
    } else {
      if (col < 128) v = wk[(size_t)d * 128 + col];
      else           v = wkc[(size_t)d * 32 + (col - 128)];
    }
    Wq[t] = f2b(v);
  } else if (b < 7368) {                            // Wsmall[a][32][2048]
    int t = (b - 7296) * 256 + tid;
    if (t >= AN * DORI) return;
    int a = t / DORI, f = t % DORI;
    u16* Wa = Wsm + (size_t)a * 32 * DORI;
    for (int c = 0; c < 4; ++c)  Wa[c * DORI + f]       = f2b(aw[((size_t)a * DORI + f) * 4 + c]);
    for (int c = 0; c < 4; ++c)  Wa[(4 + c) * DORI + f] = f2b(bb[((size_t)a * DORI + f) * 4 + c]);
    for (int c = 0; c < 21; ++c) Wa[(8 + c) * DORI + f] = f2b(cw[((size_t)a * DORI + f) * 21 + c]);
    Wa[29 * DORI + f] = f2b(awc[(size_t)a * DORI + f]);
    Wa[30 * DORI + f] = 0;
    Wa[31 * DORI + f] = 0;
  } else {                                          // gt_features f32 -> featB batch 9
    if (!featB9) return;
    long i = (long)(b - 7368) * 256 + tid;          // < NN*DORI/8 = 1048576
    float4 v0 = ((const float4*)gt)[i * 2];
    float4 v1 = ((const float4*)gt)[i * 2 + 1];
    ((uint4*)featB9)[i] = pack8(v0, v1);
  }
}

// ================= feat_gemm: smallf = features @ Wsmall^T =========================
// fused: f32->bf16 featB writeback + cls_score epilogue write. 2-deep reg prefetch.
__global__ __launch_bounds__(256) void feat_gemm(const float* __restrict__ feat,
                                                 const u16* __restrict__ Wsm,
                                                 float* __restrict__ smallf,
                                                 u16* __restrict__ wb,
                                                 float* __restrict__ cls_out) {
  __shared__ __align__(16) u16 As[64 * 32];
  __shared__ __align__(16) u16 Bs[32 * 32];
  const int tid = threadIdx.x, lane = tid & 63, wave = tid >> 6;
  const int tileM = blockIdx.y * 64, batch = blockIdx.z;
  const float* Ab = feat + ((size_t)batch * NN + tileM) * DORI;
  const u16* Bb = Wsm + (size_t)batch * 32 * DORI;
  u16* wbp = wb ? wb + ((size_t)batch * NN + tileM) * DORI : nullptr;

  f32x4 acc0 = {0.f, 0.f, 0.f, 0.f}, acc1 = {0.f, 0.f, 0.f, 0.f};
  const int arow = tid >> 2, acol = (tid & 3) * 8;
  const bool bact = tid < 128;

  uint4 raA, rbA, raB, rbB;
  auto loadA = [&](int k0) {
    const float* s = Ab + (size_t)arow * DORI + k0 + acol;
    raA = pack8(*(const float4*)s, *(const float4*)(s + 4));
    if (bact) rbA = *(const uint4*)(Bb + (size_t)arow * DORI + k0 + acol);
  };
  auto loadB = [&](int k0) {
    const float* s = Ab + (size_t)arow * DORI + k0 + acol;
    raB = pack8(*(const float4*)s, *(const float4*)(s + 4));
    if (bact) rbB = *(const uint4*)(Bb + (size_t)arow * DORI + k0 + acol);
  };
  loadA(0);
  loadB(32);
  const u16* Arow = As + (wave * 16 + (lane & 15)) * 32 + (lane >> 4) * 8;
  const u16* Brow = Bs + (lane & 15) * 32 + (lane >> 4) * 8;

  for (int k0 = 0; k0 < DORI; k0 += 64) {
    // ---- step A (k0) ----
    __syncthreads();
    *(uint4*)(As + (size_t)tid * 8) = raA;
    if (bact) *(uint4*)(Bs + (size_t)tid * 8) = rbA;
    if (wbp) *(uint4*)(wbp + (size_t)arow * DORI + k0 + acol) = raA;
    __syncthreads();
    if (k0 + 64 < DORI) loadA(k0 + 64);
    {
      s16x8 af = *(const s16x8*)Arow;
      s16x8 b0 = *(const s16x8*)Brow;
      s16x8 b1 = *(const s16x8*)(Brow + 16 * 32);
      acc0 = __builtin_amdgcn_mfma_f32_16x16x32_bf16(af, b0, acc0, 0, 0, 0);
      acc1 = __builtin_amdgcn_mfma_f32_16x16x32_bf16(af, b1, acc1, 0, 0, 0);
    }
    // ---- step B (k0+32) ----
    __syncthreads();
    *(uint4*)(As + (size_t)tid * 8) = raB;
    if (bact) *(uint4*)(Bs + (size_t)tid * 8) = rbB;
    if (wbp) *(uint4*)(wbp + (size_t)arow * DORI + k0 + 32 + acol) = raB;
    __syncthreads();
    if (k0 + 96 < DORI) loadB(k0 + 96);
    {
      s16x8 af = *(const s16x8*)Arow;
      s16x8 b0 = *(const s16x8*)Brow;
      s16x8 b1 = *(const s16x8*)(Brow + 16 * 32);
      acc0 = __builtin_amdgcn_mfma_f32_16x16x32_bf16(af, b0, acc0, 0, 0, 0);
      acc1 = __builtin_amdgcn_mfma_f32_16x16x32_bf16(af, b1, acc1, 0, 0, 0);
    }
  }

  const int r0 = tileM + wave * 16 + (lane >> 4) * 4;
  const int c0 = lane & 15;
#pragma unroll
  for (int q = 0; q < 4; ++q) {
    const size_t an = (size_t)batch * NN + r0 + q;
    smallf[an * 32 + c0]      = acc0[q];
    smallf[an * 32 + c0 + 16] = acc1[q];
    if (c0 >= 8)  cls_out[an * 21 + (c0 - 8)] = acc0[q];   // cls cols 8..15
    if (c0 <= 12) cls_out[an * 21 + (c0 + 8)] = acc1[q];   // cls cols 16..28
  }
}

// ================= bf16 GEMM with global_load_lds staging ==========================
// C[M,N] = A[M,K] * Bt[N,K]^T ; all bf16 operands
template<int BM, int BN, int WM, int WN, bool RELU, bool OUTBF, bool SWZ>
__global__ __launch_bounds__(WM * WN * 64)
void gemm_glds(const u16* __restrict__ A, long sA, const u16* __restrict__ B, long sB,
               void* __restrict__ Cv, long sC, int N, int K) {
  constexpr int THREADS = WM * WN * 64;
  constexpr int WTM = BM / WM, WTN = BN / WN;
  constexpr int FM = WTM / 16, FN = WTN / 16;
  constexpr int ACHN = BM * 4, BCHN = BN * 4;
  constexpr int ACH = (ACHN + THREADS - 1) / THREADS;
  constexpr int BCH = (BCHN + THREADS - 1) / THREADS;
  constexpr bool AFULL = (ACHN % THREADS) == 0, BFULL = (BCHN % THREADS) == 0;

  __shared__ __align__(16) u16 As[BM * 32];
  __shared__ __align__(16) u16 Bs[BN * 32];

  int bx = blockIdx.x, by = blockIdx.y, bz = blockIdx.z;
  if constexpr (SWZ) {   // chunked XCD swizzle (nwg % 8 == 0 required)
    int gx = gridDim.x, gy = gridDim.y;
    int h = bx + gx * (by + gy * bz);
    int nwg = gx * gy * (int)gridDim.z;
    int cpx = nwg >> 3;
    int l = (h & 7) * cpx + (h >> 3);
    bx = l % gx; l /= gx; by = l % gy; bz = l / gy;
  }

  const int tid = threadIdx.x, lane = tid & 63, wave = tid >> 6;
  const int wm = wave % WM, wn = wave / WM;
  const int tileN = bx * BN, tileM = by * BM;
  const u16* Ab = A + (size_t)bz * sA + (size_t)tileM * K;
  const u16* Bb = B + (size_t)bz * sB + (size_t)tileN * K;

  f32x4 acc[FM][FN];
#pragma unroll
  for (int i = 0; i < FM; ++i)
#pragma unroll
    for (int j = 0; j < FN; ++j) acc[i][j] = (f32x4){0.f, 0.f, 0.f, 0.f};

  const u16* Arow = As + (wm * WTM + (lane & 15)) * 32 + (lane >> 4) * 8;
  const u16* Brow = Bs + (wn * WTN + (lane & 15)) * 32 + (lane >> 4) * 8;

  for (int k0 = 0; k0 < K; k0 += 32) {
#pragma unroll
    for (int i = 0; i < ACH; ++i) {
      int c = tid + i * THREADS;
      if (AFULL || c < ACHN)
        gload_lds16(Ab + (size_t)(c >> 2) * K + k0 + (c & 3) * 8, As + c * 8);
    }
#pragma unroll
    for (int i = 0; i < BCH; ++i) {
      int c = tid + i * THREADS;
      if (BFULL || c < BCHN)
        gload_lds16(Bb + (size_t)(c >> 2) * K + k0 + (c & 3) * 8, Bs + c * 8);
    }
    __syncthreads();
    s16x8 af[FM], bfr[FN];
#pragma unroll
    for (int i = 0; i < FM; ++i) af[i] = *(const s16x8*)(Arow + i * 16 * 32);
#pragma unroll
    for (int j = 0; j < FN; ++j) bfr[j] = *(const s16x8*)(Brow + j * 16 * 32);
#pragma unroll
    for (int i = 0; i < FM; ++i)
#pragma unroll
      for (int j = 0; j < FN; ++j)
        acc[i][j] = __builtin_amdgcn_mfma_f32_16x16x32_bf16(af[i], bfr[j], acc[i][j], 0, 0, 0);
    __syncthreads();
  }

  const int r0 = tileM + wm * WTM + (lane >> 4) * 4;
  const int c0 = tileN + wn * WTN + (lane & 15);
#pragma unroll
  for (int i = 0; i < FM; ++i)
#pragma unroll
    for (int j = 0; j < FN; ++j)
#pragma unroll
      for (int q = 0; q < 4; ++q) {
        float v = acc[i][j][q];
        if (RELU) v = fmaxf(v, 0.f);
        size_t idx = (size_t)bz * sC + (size_t)(r0 + i * 16 + q) * N + (c0 + j * 16);
        if (OUTBF) ((u16*)Cv)[idx] = f2b(v);
        else       ((float*)Cv)[idx] = v;
      }
}

// ================= fallback gemm1 (A = f32, reg-staged pack) =======================
template<int BM, int BN, int WM, int WN, bool RELU, bool OUTBF>
__global__ __launch_bounds__(WM * WN * 64)
void gemm_af32(const float* __restrict__ Av, const float* __restrict__ A2v, long sA,
               const u16* __restrict__ B, long sB,
               void* __restrict__ Cv, long sC, int N, int K) {
  constexpr int THREADS = WM * WN * 64;
  constexpr int WTM = BM / WM, WTN = BN / WN;
  constexpr int FM = WTM / 16, FN = WTN / 16;
  constexpr int ACH = (BM * 4) / THREADS;
  constexpr int BCHN = BN * 4;
  constexpr int BCH = (BCHN + THREADS - 1) / THREADS;
  constexpr bool BFULL = (BCHN % THREADS) == 0;

  __shared__ __align__(16) u16 As[BM * 32];
  __shared__ __align__(16) u16 Bs[BN * 32];

  const int tid = threadIdx.x, lane = tid & 63, wave = tid >> 6;
  const int wm = wave % WM, wn = wave / WM;
  const int tileN = blockIdx.x * BN, tileM = blockIdx.y * BM;
  const int batch = blockIdx.z;
  const float* base = (batch < 9) ? (Av + (size_t)batch * sA) : A2v;
  const float* Ab32 = base + (size_t)tileM * K;
  const u16* Bb = B + (size_t)batch * sB + (size_t)tileN * K;

  f32x4 acc[FM][FN];
#pragma unroll
  for (int i = 0; i < FM; ++i)
#pragma unroll
    for (int j = 0; j < FN; ++j) acc[i][j] = (f32x4){0.f, 0.f, 0.f, 0.f};

  uint4 ra[ACH], rb[BCH];
  auto load_t = [&](int k0) {
#pragma unroll
    for (int i = 0; i < ACH; ++i) {
      int c = tid + i * THREADS;
      const float* s = Ab32 + (size_t)(c >> 2) * K + k0 + (c & 3) * 8;
      ra[i] = pack8(*(const float4*)s, *(const float4*)(s + 4));
    }
#pragma unroll
    for (int i = 0; i < BCH; ++i) {
      int c = tid + i * THREADS;
      if (BFULL || c < BCHN)
        rb[i] = *(const uint4*)(Bb + (size_t)(c >> 2) * K + k0 + (c & 3) * 8);
    }
  };

  load_t(0);
  const u16* Arow = As + (wm * WTM + (lane & 15)) * 32 + (lane >> 4) * 8;
  const u16* Brow = Bs + (wn * WTN + (lane & 15)) * 32 + (lane >> 4) * 8;

  for (int k0 = 0; k0 < K; k0 += 32) {
    __syncthreads();
#pragma unroll
    for (int i = 0; i < ACH; ++i)
      *(uint4*)(As + (size_t)(tid + i * THREADS) * 8) = ra[i];
#pragma unroll
    for (int i = 0; i < BCH; ++i) {
      int c = tid + i * THREADS;
      if (BFULL || c < BCHN) *(uint4*)(Bs + (size_t)c * 8) = rb[i];
    }
    __syncthreads();
    if (k0 + 32 < K) load_t(k0 + 32);
    s16x8 af[FM], bfr[FN];
#pragma unroll
    for (int i = 0; i < FM; ++i) af[i] = *(const s16x8*)(Arow + i * 16 * 32);
#pragma unroll
    for (int j = 0; j < FN; ++j) bfr[j] = *(const s16x8*)(Brow + j * 16 * 32);
#pragma unroll
    for (int i = 0; i < FM; ++i)
#pragma unroll
      for (int j = 0; j < FN; ++j)
        acc[i][j] = __builtin_amdgcn_mfma_f32_16x16x32_bf16(af[i], bfr[j], acc[i][j], 0, 0, 0);
  }

  const int r0 = tileM + wm * WTM + (lane >> 4) * 4;
  const int c0 = tileN + wn * WTN + (lane & 15);
#pragma unroll
  for (int i = 0; i < FM; ++i)
#pragma unroll
    for (int j = 0; j < FN; ++j)
#pragma unroll
      for (int q = 0; q < 4; ++q) {
        float v = acc[i][j][q];
        if (RELU) v = fmaxf(v, 0.f);
        size_t idx = (size_t)batch * sC + (size_t)(r0 + i * 16 + q) * N + (c0 + j * 16);
        if (OUTBF) ((u16*)Cv)[idx] = f2b(v);
        else       ((float*)Cv)[idx] = v;
      }
}

// ================= fused q-projection + beta epilogue ==============================
// per block: 128 rows x full 160 cols of q = off[a] @ Wq[a]^T, then
// beta[a,n,c] = scale * sum_{cols=c mod 4, <128} q*key - iou ; cls from cols 128-159
__global__ __launch_bounds__(256) void gemm2qb(const u16* __restrict__ offb,
                                               const u16* __restrict__ Wq,
                                               const float* __restrict__ keyf,
                                               const float* __restrict__ ious,
                                               float* __restrict__ betaf,
                                               float* __restrict__ betac) {
  constexpr int BM = 128, BN = 160;
  __shared__ __align__(16) u16 As[BM * 32];
  __shared__ __align__(16) u16 Bs[BN * 32];
  const int tid = threadIdx.x, lane = tid & 63, wave = tid >> 6;  // 4 waves on M
  const int tileM = blockIdx.x * BM;
  const int a = blockIdx.y;
  const u16* Ab = offb + ((size_t)a * NN + tileM) * DAPP;
  const u16* Bb = Wq + (size_t)a * QCOLS * DAPP;

  f32x4 acc[2][10];
#pragma unroll
  for (int i = 0; i < 2; ++i)
#pragma unroll
    for (int j = 0; j < 10; ++j) acc[i][j] = (f32x4){0.f, 0.f, 0.f, 0.f};

  const u16* Arow = As + (wave * 32 + (lane & 15)) * 32 + (lane >> 4) * 8;
  const u16* Brow = Bs + (lane & 15) * 32 + (lane >> 4) * 8;

  for (int k0 = 0; k0 < DAPP; k0 += 32) {
#pragma unroll
    for (int i = 0; i < 2; ++i) {          // ACHN = 512
      int c = tid + i * 256;
      gload_lds16(Ab + (size_t)(c >> 2) * DAPP + k0 + (c & 3) * 8, As + c * 8);
    }
#pragma unroll
    for (int i = 0; i < 3; ++i) {          // BCHN = 640
      int c = tid + i * 256;
      if (c < 640)
        gload_lds16(Bb + (size_t)(c >> 2) * DAPP + k0 + (c & 3) * 8, Bs + c * 8);
    }
    __syncthreads();
    s16x8 af[2], bfr[10];
#pragma unroll
    for (int i = 0; i < 2; ++i) af[i] = *(const s16x8*)(Arow + i * 16 * 32);
#pragma unroll
    for (int j = 0; j < 10; ++j) bfr[j] = *(const s16x8*)(Brow + j * 16 * 32);
#pragma unroll
    for (int i = 0; i < 2; ++i)
#pragma unroll
      for (int j = 0; j < 10; ++j)
        acc[i][j] = __builtin_amdgcn_mfma_f32_16x16x32_bf16(af[i], bfr[j], acc[i][j], 0, 0, 0);
    __syncthreads();
  }

  const float scale = 0.17677669529663687f;  // 1/sqrt(32)
  const int cg = lane & 15;
#pragma unroll
  for (int i = 0; i < 2; ++i)
#pragma unroll
    for (int q = 0; q < 4; ++q) {
      const int row = tileM + wave * 32 + i * 16 + (lane >> 4) * 4 + q;
      const float* kr = keyf + (size_t)row * QCOLS;
      float m = 0.f;
#pragma unroll
      for (int j = 0; j < 8; ++j) m += acc[i][j][q] * kr[cg + j * 16];
      float cl = acc[i][8][q] * kr[128 + cg] + acc[i][9][q] * kr[144 + cg];
      m += __shfl_xor(m, 4); m += __shfl_xor(m, 8);
      cl += __shfl_xor(cl, 1); cl += __shfl_xor(cl, 2);
      cl += __shfl_xor(cl, 4); cl += __shfl_xor(cl, 8);
      const float iou = ious[(size_t)a * NN + row];
      if (cg < 4)  betaf[((size_t)a * NN + row) * 4 + (lane & 3)] = m * scale - iou;
      if (cg == 0) betac[(size_t)a * NN + row] = cl * scale - iou;
    }
}

// ================= softmaxes + outputs (all f32), thread per n =====================
__global__ __launch_bounds__(256) void finalize(const float* __restrict__ smallf,
                                                const float* __restrict__ beta_ws,
                                                const float* __restrict__ betac_ws,
                                                const float* __restrict__ delta_rois,
                                                float* __restrict__ out) {
  int n = blockIdx.x * blockDim.x + threadIdx.x;
  if (n >= NN) return;

  for (int c = 0; c < 4; ++c) {
    float al[9], be[9], dp[9];
    float mA = -1e30f, mB = -1e30f;
    for (int a = 0; a < 9; ++a) {
      size_t an = (size_t)a * NN + n;
      al[a] = smallf[an * 32 + c];
      float off_ = smallf[an * 32 + 4 + c];
      dp[a] = delta_rois[an * 5 + 1 + c] + off_;
      be[a] = beta_ws[an * 4 + c];
      mA = fmaxf(mA, al[a]); mB = fmaxf(mB, be[a]);
    }
    float eA[9], eB[9], sA = 0.f, sB = 0.f;
    for (int a = 0; a < 9; ++a) {
      eA[a] = expf(al[a] - mA); sA += eA[a];
      eB[a] = expf(be[a] - mB); sB += eB[a];
    }
    float rA = 1.f / sA, rB = 1.f / sB;
    float ov = 0.f, obv = 0.f;
    for (int a = 0; a < 9; ++a) {
      size_t an = (size_t)a * NN + n;
      float as_ = eA[a] * rA, bs_ = eB[a] * rB;
      out[O2 + an * 4 + c] = as_;
      out[O3 + an * 4 + c] = bs_;
      out[O4 + an * 4 + c] = dp[a];
      out[O5 + an * 4 + c] = dp[a];
      out[O6 + an * 4 + c] = al[a];
      out[O7 + an * 4 + c] = be[a];
      ov += dp[a] * as_; obv += dp[a] * bs_;
    }
    out[O0 + (size_t)n * 4 + c] = ov;
    out[O1 + (size_t)n * 4 + c] = obv;
  }

  float ac[9], bc[9];
  float mA = -1e30f, mB = -1e30f;
  for (int a = 0; a < 9; ++a) {
    size_t an = (size_t)a * NN + n;
    ac[a] = smallf[an * 32 + 29];
    bc[a] = betac_ws[an];
    mA = fmaxf(mA, ac[a]); mB = fmaxf(mB, bc[a]);
  }
  float eA[9], eB[9], sA = 0.f, sB = 0.f;
  for (int a = 0; a < 9; ++a) {
    eA[a] = expf(ac[a] - mA); sA += eA[a];
    eB[a] = expf(bc[a] - mB); sB += eB[a];
  }
  float rA = 1.f / sA, rB = 1.f / sB;
  for (int a = 0; a < 9; ++a) {
    size_t an = (size_t)a * NN + n;
    out[O9 + an]  = eA[a] * rA;
    out[O10 + an] = eB[a] * rB;
    out[O11 + an] = ac[a];
    out[O12 + an] = bc[a];
  }
}

extern "C" void kernel_launch(void* const* d_in, const int* in_sizes, int n_in,
                              void* d_out, int out_size, void* d_ws, size_t ws_size,
                              hipStream_t stream) {
  const float* delta_rois = (const float*)d_in[1];
  const float* features   = (const float*)d_in[2];
  const float* gt_features= (const float*)d_in[3];
  const float* ious       = (const float*)d_in[4];
  const float* att        = (const float*)d_in[5];
  const float* w_k        = (const float*)d_in[6];
  const float* w_q        = (const float*)d_in[7];
  const float* alpha_w    = (const float*)d_in[8];
  const float* bbox       = (const float*)d_in[9];
  const float* w_k_cls    = (const float*)d_in[10];
  const float* w_q_cls    = (const float*)d_in[11];
  const float* alpha_w_cls= (const float*)d_in[12];
  const float* cls_w      = (const float*)d_in[13];
  float* out = (float*)d_out;

  char* ws = (char*)d_ws;
  u16* attB    = (u16*)ws;   ws += (size_t)DAPP * DORI * 2;       // 2.1 MB
  u16* Wq      = (u16*)ws;   ws += (size_t)NB * QCOLS * DAPP * 2; // 1.6 MB
  u16* Wsmall  = (u16*)ws;   ws += (size_t)AN * 32 * DORI * 2;    // 1.2 MB
  u16* offb    = (u16*)ws;   ws += (size_t)NB * NN * DAPP * 2;    // 42 MB (batch9 = gt_off)
  float* smallf= (float*)ws; ws += (size_t)AN * NN * 32 * 4;      // 4.7 MB
  float* keyf  = (float*)ws; ws += (size_t)NN * QCOLS * 4;        // 2.6 MB
  float* betaf = (float*)ws; ws += (size_t)AN * NN * 4 * 4;       // 2.4 MB
  float* betac = (float*)ws; ws += (size_t)AN * NN * 4;           // 0.15 MB
  size_t base_bytes = (size_t)(ws - (char*)d_ws);
  size_t featB_bytes = (size_t)NB * NN * DORI * 2;                // 168 MB
  bool big = ws_size >= base_bytes + featB_bytes;
  u16* featB = big ? (u16*)ws : nullptr;

  // 1. fused prep (att transpose, Wq pack, Wsmall pack, gt cast)
  prep<<<11464, 256, 0, stream>>>(att, w_q, w_q_cls, w_k, w_k_cls, alpha_w, bbox,
                                  alpha_w_cls, cls_w, gt_features, attB, Wq, Wsmall,
                                  big ? featB + (size_t)AN * NN * DORI : nullptr);

  // 2. small path + featB writeback + cls out
  dim3 gf(1, NN / 64, AN);
  feat_gemm<<<gf, 256, 0, stream>>>(features, Wsmall, smallf, featB, out + O8);

  // 3. off = relu(feat @ attB^T)  [10 batches, batch9 = gt]
  dim3 g1(DAPP / 128, NN / 128, NB);
  if (big) {
    gemm_glds<128, 128, 2, 2, true, true, true><<<g1, 256, 0, stream>>>(
        featB, (long)NN * DORI, attB, 0, offb, (long)NN * DAPP, DAPP, DORI);
  } else {
    gemm_af32<128, 128, 2, 2, true, true><<<g1, 256, 0, stream>>>(
        features, gt_features, (long)NN * DORI, attB, 0, offb, (long)NN * DAPP, DAPP, DORI);
  }

  // 4. key = gt_off @ Wq[9]^T  (batch 9 only) -> keyf f32
  dim3 gk(QCOLS / 32, NN / 128, 1);
  gemm_glds<128, 32, 4, 1, false, false, false><<<gk, 256, 0, stream>>>(
      offb + (size_t)9 * NN * DAPP, 0, Wq + (size_t)9 * QCOLS * DAPP, 0,
      keyf, 0, QCOLS, DAPP);

  // 5. fused q-projection + beta (batches 0-8)
  dim3 g2(NN / 128, AN, 1);
  gemm2qb<<<g2, 256, 0, stream>>>(offb, Wq, keyf, ious, betaf, betac);

  // 6. softmaxes + outputs
  finalize<<<NN / 256, 256, 0, stream>>>(smallf, betaf, betac, delta_rois, out);
}